// Round 5
// baseline (333.866 us; speedup 1.0000x reference)
//
#include <hip/hip_runtime.h>
#include <hip/hip_bf16.h>
#include <stdint.h>

// out[m][n] = sum_k x[m][k] * centroids[idx[n][k]] + bias[n]
// M=8192, N=4096, K=4096. decode W->bf16, cvt x->bf16, then 256x256 8-phase
// MFMA GEMM. Round 5: full-tile prefetch slack — A triple-buffered (96 KiB),
// B double-buffered (64 KiB) = 160 KiB LDS; all loads for tile T+1 are issued
// during tile T-1; p3 waits vmcnt(8) (leaves T+2's 8 loads in flight).

typedef unsigned short u16;
typedef __attribute__((ext_vector_type(8))) short short8;   // bf16x8 (4 VGPR)
typedef __attribute__((ext_vector_type(8))) u16   u16x8;
typedef __attribute__((ext_vector_type(4))) float f32x4;
typedef __attribute__((ext_vector_type(4))) int   i32x4;

constexpr int Mdim = 8192;
constexpr int Ndim = 4096;
constexpr int Kdim = 4096;

__device__ __forceinline__ u16 f2bf(float f) {
  union { float f; uint32_t u; } v; v.f = f;
  uint32_t u = v.u;
  return (u16)((u + 0x7fffu + ((u >> 16) & 1u)) >> 16);
}

// ---------------- decode: weight_bf16[n*K + k] = bf16(cent[idx[n*K + k]]) ----
__global__ void decode_weight_kernel(const int* __restrict__ idx,
                                     const float* __restrict__ cent,
                                     u16* __restrict__ wb) {
  __shared__ u16 lut[256];
  const int t = threadIdx.x;
  if (t < 256) lut[t] = f2bf(cent[t]);
  __syncthreads();
  const size_t base = ((size_t)blockIdx.x * 256 + t) * 8;
  i32x4 i0 = *(const i32x4*)(idx + base);
  i32x4 i1 = *(const i32x4*)(idx + base + 4);
  u16x8 r;
  r[0] = lut[i0[0] & 255]; r[1] = lut[i0[1] & 255];
  r[2] = lut[i0[2] & 255]; r[3] = lut[i0[3] & 255];
  r[4] = lut[i1[0] & 255]; r[5] = lut[i1[1] & 255];
  r[6] = lut[i1[2] & 255]; r[7] = lut[i1[3] & 255];
  *(u16x8*)(wb + base) = r;
}

// ---------------- convert: x fp32 -> bf16 -----------------------------------
__global__ void cvt_x_kernel(const float* __restrict__ x, u16* __restrict__ xb) {
  const size_t base = ((size_t)blockIdx.x * 256 + threadIdx.x) * 8;
  f32x4 a = *(const f32x4*)(x + base);
  f32x4 b = *(const f32x4*)(x + base + 4);
  u16x8 r;
  r[0] = f2bf(a[0]); r[1] = f2bf(a[1]); r[2] = f2bf(a[2]); r[3] = f2bf(a[3]);
  r[4] = f2bf(b[0]); r[5] = f2bf(b[1]); r[6] = f2bf(b[2]); r[7] = f2bf(b[3]);
  *(u16x8*)(xb + base) = r;
}

// ---------------- async 16B global -> LDS -----------------------------------
__device__ __forceinline__ void async16(const u16* g, u16* l) {
  __builtin_amdgcn_global_load_lds(
      (const __attribute__((address_space(1))) void*)g,
      (__attribute__((address_space(3))) void*)l,
      16, 0, 0);
}

#define BAR()   __builtin_amdgcn_s_barrier()
#define SCB()   __builtin_amdgcn_sched_barrier(0)
#define LGKM0() do { asm volatile("s_waitcnt lgkmcnt(0)" ::: "memory"); SCB(); } while (0)
#define LGKM4() do { asm volatile("s_waitcnt lgkmcnt(4)" ::: "memory"); SCB(); } while (0)
#define VMC8()  asm volatile("s_waitcnt vmcnt(8)" ::: "memory")
#define VMC0()  asm volatile("s_waitcnt vmcnt(0)" ::: "memory")

// ---------------- 256x256 8-phase bf16 GEMM ---------------------------------
// 512 threads = 8 waves (2 M-waves x 4 N-waves). BK=64.
// LDS: A 3 bufs x 32 KiB + B 2 bufs x 32 KiB = 160 KiB (1 block/CU).
// LDS per half: 16x32-elem subtiles (1 KiB); quad slot = (col>>3) ^ ((r>>1)&3).
// Staging during tile T targets T+2 (p0: A-h0, p1: A-h1, p2: B-h0, p3: B-h1);
// p3 waits vmcnt(8) -> everything for T+1 (issued during T-1) has landed.
__global__ __launch_bounds__(512, 2)
void gemm_bf16_kernel(const u16* __restrict__ A,   // [Mdim][Kdim] bf16
                      const u16* __restrict__ B,   // [Ndim][Kdim] bf16
                      const float* __restrict__ bias,
                      float* __restrict__ C) {
  __shared__ u16 AsF[49152];   // 3 bufs x 16384 elems = 96 KiB
  __shared__ u16 BsF[32768];   // 2 bufs x 16384 elems = 64 KiB

  const int t    = threadIdx.x;
  const int lane = t & 63;
  const int w    = t >> 6;      // wave 0..7
  const int wm   = w >> 2;      // 0..1  -> A rows wm*128..+127
  const int wn   = w & 3;       // 0..3  -> B rows wn*64..+63
  const int fr   = lane & 15;
  const int fq   = lane >> 4;
  const int cswz = (fr & 6) << 2;   // ((fr>>1)&3)*8

  // T1: XCD-aware block swizzle (512 blocks, 512%8==0 -> simple form OK)
  const int bid = blockIdx.x;
  const int swz = (bid & 7) * 64 + (bid >> 3);
  const int m0 = (swz >> 4) * 256;   // 32 M-tiles
  const int n0 = (swz & 15) * 256;   // 16 N-tiles

  // staging geometry: chunk c = l*512 + w*64 + lane (16 B each), LDS linear.
  const int c0   = w * 64 + lane;                    // chunk for l=0
  const int r16s = (c0 & 63) >> 2;
  const int srow = ((c0 >> 7) << 4) + r16s;          // 0..63 (l=1 -> +64)
  const int scol = ((c0 >> 6) & 1) * 32 + (((c0 & 3) * 8) ^ ((r16s & 6) << 2));
  const u16* pA = A + (size_t)(m0 + srow) * Kdim + scol;
  const u16* pB = B + (size_t)(n0 + srow) * Kdim + scol;
  const int dsto = c0 * 8;                           // LDS elem offset

  // fragment read offsets (elements): (rt*2+kk)*512 + fr*32 + swizzled col
  const int aoff = wm * 8192 + fr * 32 + ((fq * 8) ^ cswz);
  const int boff = (wn >> 1) * 8192 + (wn & 1) * 4096 + fr * 32 + ((fq * 8) ^ cswz);

  f32x4 acc[8][4] = {};
  short8 bf[2][4];      // [kk][ni], refreshed at tile boundary
  short8 afA[2][2];     // even-q A frags (q0, q2)
  short8 afB[2][2];     // odd-q  A frags (q1, q3)

  auto stageA = [&](int tk, int h, int buf) {
    const u16* s = pA + (size_t)h * (128 * Kdim) + tk * 64;
    u16* d = &AsF[buf * 16384 + h * 8192 + dsto];
    async16(s, d);
    async16(s + (size_t)(64 * Kdim), d + 4096);
  };
  auto stageB = [&](int tk, int h, int buf) {
    const u16* s = pB + (size_t)h * (128 * Kdim) + tk * 64;
    u16* d = &BsF[buf * 16384 + h * 8192 + dsto];
    async16(s, d);
    async16(s + (size_t)(64 * Kdim), d + 4096);
  };
  auto rdB_kk = [&](int buf, int kk) {
#pragma unroll
    for (int ni = 0; ni < 4; ++ni)
      bf[kk][ni] = *(const short8*)&BsF[buf * 16384 + boff + (ni * 2 + kk) * 512];
  };
  auto rdA_A = [&](int buf, int q) {
#pragma unroll
    for (int kk = 0; kk < 2; ++kk)
#pragma unroll
      for (int i = 0; i < 2; ++i)
        afA[kk][i] = *(const short8*)&AsF[buf * 16384 + aoff + ((q * 2 + i) * 2 + kk) * 512];
  };
  auto rdA_B = [&](int buf, int q) {
#pragma unroll
    for (int kk = 0; kk < 2; ++kk)
#pragma unroll
      for (int i = 0; i < 2; ++i)
        afB[kk][i] = *(const short8*)&AsF[buf * 16384 + aoff + ((q * 2 + i) * 2 + kk) * 512];
  };
  auto mfmaE = [&](int q) {   // uses afA
    __builtin_amdgcn_s_setprio(1);
#pragma unroll
    for (int kk = 0; kk < 2; ++kk)
#pragma unroll
      for (int i = 0; i < 2; ++i)
#pragma unroll
        for (int ni = 0; ni < 4; ++ni)
          acc[q * 2 + i][ni] = __builtin_amdgcn_mfma_f32_16x16x32_bf16(
              afA[kk][i], bf[kk][ni], acc[q * 2 + i][ni], 0, 0, 0);
    __builtin_amdgcn_s_setprio(0);
  };
  auto mfmaO = [&](int q) {   // uses afB
    __builtin_amdgcn_s_setprio(1);
#pragma unroll
    for (int kk = 0; kk < 2; ++kk)
#pragma unroll
      for (int i = 0; i < 2; ++i)
#pragma unroll
        for (int ni = 0; ni < 4; ++ni)
          acc[q * 2 + i][ni] = __builtin_amdgcn_mfma_f32_16x16x32_bf16(
              afB[kk][i], bf[kk][ni], acc[q * 2 + i][ni], 0, 0, 0);
    __builtin_amdgcn_s_setprio(0);
  };
  auto mfmaO_kk = [&](int q, int kk) {   // one kk-half of an odd q
    __builtin_amdgcn_s_setprio(1);
#pragma unroll
    for (int i = 0; i < 2; ++i)
#pragma unroll
      for (int ni = 0; ni < 4; ++ni)
        acc[q * 2 + i][ni] = __builtin_amdgcn_mfma_f32_16x16x32_bf16(
            afB[kk][i], bf[kk][ni], acc[q * 2 + i][ni], 0, 0, 0);
    __builtin_amdgcn_s_setprio(0);
  };

  // Tile T. Entry invariant: afA = q0 frags; bf = B(T); boundary 12 ds_reads
  // in flight; vmem outstanding = 8 = A(T+1)+B(T+1).
  // mode: 0 normal (stage T+2, vmcnt(8)); 1 tile 62 (no stage, vmcnt(0));
  //       2 tile 63 (no stage, no vmcnt, no boundary reads).
  auto tile = [&](int tk, int ab, int bb, int mode) {
    const int abN = (ab == 2) ? 0 : ab + 1;   // (ab+1)%3 : buffer of tile T+1
    const int ab2 = (abN == 2) ? 0 : abN + 1; // (ab+2)%3 : buffer of tile T+2
    // p0
    rdA_B(ab, 1);
    if (mode == 0) stageA(tk + 2, 0, ab2);
    BAR(); LGKM4();          // boundary 12 done; q1 reads in flight
    mfmaE(0);
    BAR();
    // p1
    rdA_A(ab, 2);
    if (mode == 0) stageA(tk + 2, 1, ab2);
    BAR(); LGKM4();          // q1 done
    mfmaO(1);
    BAR();
    // p2
    rdA_B(ab, 3);
    if (mode == 0) stageB(tk + 2, 0, bb);
    BAR(); LGKM4();          // q2 done
    mfmaE(2);
    BAR();
    // p3: boundary
    if (mode == 0) { stageB(tk + 2, 1, bb); VMC8(); }
    else if (mode == 1) { VMC0(); }
    BAR();                   // all waves: A(T+1)/B(T+1) landed in LDS
    LGKM0();                 // q3 reads done
    mfmaO_kk(3, 0);
    if (mode < 2) rdB_kk(bb ^ 1, 0);
    mfmaO_kk(3, 1);
    if (mode < 2) { rdB_kk(bb ^ 1, 1); rdA_A(abN, 0); }
    BAR();
  };

  // Prologue: A(0),B(0) then A(1),B(1); vmcnt(8) -> A(0),B(0) landed;
  // boundary reads for tile 0. Leaves 8 in flight = A(1)+B(1)  (invariant).
  stageA(0, 0, 0); stageA(0, 1, 0); stageB(0, 0, 0); stageB(0, 1, 0);
  stageA(1, 0, 1); stageA(1, 1, 1); stageB(1, 0, 1); stageB(1, 1, 1);
  VMC8();
  BAR();
  rdB_kk(0, 0); rdB_kk(0, 1); rdA_A(0, 0);

  int ab = 0;
  for (int tk = 0; tk < 62; ++tk) {
    tile(tk, ab, tk & 1, 0);
    ab = (ab == 2) ? 0 : ab + 1;
  }
  tile(62, 2, 0, 1);   // 62%3=2, 62&1=0: drain vmcnt
  tile(63, 0, 1, 2);   // 63%3=0, 63&1=1: last tile

  // Epilogue: C/D map col=lane&15, row=(lane>>4)*4+j  [m89]
  float bv[4];
#pragma unroll
  for (int ni = 0; ni < 4; ++ni)
    bv[ni] = bias[n0 + wn * 64 + ni * 16 + fr];

#pragma unroll
  for (int mi = 0; mi < 8; ++mi) {
#pragma unroll
    for (int j = 0; j < 4; ++j) {
      const int row = m0 + wm * 128 + mi * 16 + fq * 4 + j;
      float* cp = C + (size_t)row * Ndim + n0 + wn * 64 + fr;
#pragma unroll
      for (int ni = 0; ni < 4; ++ni)
        cp[ni * 16] = acc[mi][ni][j] + bv[ni];
    }
  }
}

extern "C" void kernel_launch(void* const* d_in, const int* in_sizes, int n_in,
                              void* d_out, int out_size, void* d_ws, size_t ws_size,
                              hipStream_t stream) {
  const float* x    = (const float*)d_in[0];   // [8192][4096] fp32
  const float* cent = (const float*)d_in[1];   // [256] fp32
  const float* bias = (const float*)d_in[2];   // [4096] fp32
  const int*   idx  = (const int*)d_in[3];     // [4096][4096] int
  float* out = (float*)d_out;                  // [8192][4096] fp32

  u16* wb = (u16*)d_ws;
  u16* xb = (u16*)((char*)d_ws + (size_t)Ndim * Kdim * sizeof(u16));

  decode_weight_kernel<<<(Ndim * Kdim) / (256 * 8), 256, 0, stream>>>(idx, cent, wb);
  cvt_x_kernel<<<((size_t)Mdim * Kdim) / (256 * 8), 256, 0, stream>>>(x, xb);

  gemm_bf16_kernel<<<dim3(512), 512, 0, stream>>>(xb, wb, bias, out);
}

// Round 6
// 282.836 us; speedup vs baseline: 1.1804x; 1.1804x over previous
//
#include <hip/hip_runtime.h>
#include <hip/hip_bf16.h>
#include <stdint.h>

// out[m][n] = sum_k x[m][k] * centroids[idx[n][k]] + bias[n]
// M=8192, N=4096, K=4096. decode W->bf16, cvt x->bf16, then 256x256 MFMA GEMM.
// Round 6: r4 structure with per-phase barriers REMOVED — exactly one
// vmcnt(4)+s_barrier per K-tile. Waves free-run within a tile (own-wave
// counted lgkmcnt orders ds_reads); the single barrier broadcasts staged-data
// visibility for the buffer swap.

typedef unsigned short u16;
typedef __attribute__((ext_vector_type(8))) short short8;   // bf16x8 (4 VGPR)
typedef __attribute__((ext_vector_type(8))) u16   u16x8;
typedef __attribute__((ext_vector_type(4))) float f32x4;
typedef __attribute__((ext_vector_type(4))) int   i32x4;

constexpr int Mdim = 8192;
constexpr int Ndim = 4096;
constexpr int Kdim = 4096;

__device__ __forceinline__ u16 f2bf(float f) {
  union { float f; uint32_t u; } v; v.f = f;
  uint32_t u = v.u;
  return (u16)((u + 0x7fffu + ((u >> 16) & 1u)) >> 16);
}

// ---------------- decode: weight_bf16[n*K + k] = bf16(cent[idx[n*K + k]]) ----
__global__ void decode_weight_kernel(const int* __restrict__ idx,
                                     const float* __restrict__ cent,
                                     u16* __restrict__ wb) {
  __shared__ u16 lut[256];
  const int t = threadIdx.x;
  if (t < 256) lut[t] = f2bf(cent[t]);
  __syncthreads();
  const size_t base = ((size_t)blockIdx.x * 256 + t) * 8;
  i32x4 i0 = *(const i32x4*)(idx + base);
  i32x4 i1 = *(const i32x4*)(idx + base + 4);
  u16x8 r;
  r[0] = lut[i0[0] & 255]; r[1] = lut[i0[1] & 255];
  r[2] = lut[i0[2] & 255]; r[3] = lut[i0[3] & 255];
  r[4] = lut[i1[0] & 255]; r[5] = lut[i1[1] & 255];
  r[6] = lut[i1[2] & 255]; r[7] = lut[i1[3] & 255];
  *(u16x8*)(wb + base) = r;
}

// ---------------- convert: x fp32 -> bf16 -----------------------------------
__global__ void cvt_x_kernel(const float* __restrict__ x, u16* __restrict__ xb) {
  const size_t base = ((size_t)blockIdx.x * 256 + threadIdx.x) * 8;
  f32x4 a = *(const f32x4*)(x + base);
  f32x4 b = *(const f32x4*)(x + base + 4);
  u16x8 r;
  r[0] = f2bf(a[0]); r[1] = f2bf(a[1]); r[2] = f2bf(a[2]); r[3] = f2bf(a[3]);
  r[4] = f2bf(b[0]); r[5] = f2bf(b[1]); r[6] = f2bf(b[2]); r[7] = f2bf(b[3]);
  *(u16x8*)(xb + base) = r;
}

// ---------------- async 16B global -> LDS -----------------------------------
__device__ __forceinline__ void async16(const u16* g, u16* l) {
  __builtin_amdgcn_global_load_lds(
      (const __attribute__((address_space(1))) void*)g,
      (__attribute__((address_space(3))) void*)l,
      16, 0, 0);
}

#define BAR()   __builtin_amdgcn_s_barrier()
#define SCB()   __builtin_amdgcn_sched_barrier(0)
#define LGKM0() do { asm volatile("s_waitcnt lgkmcnt(0)" ::: "memory"); SCB(); } while (0)
#define LGKM4() do { asm volatile("s_waitcnt lgkmcnt(4)" ::: "memory"); SCB(); } while (0)
#define VMC4()  asm volatile("s_waitcnt vmcnt(4)" ::: "memory")
#define VMC0()  asm volatile("s_waitcnt vmcnt(0)" ::: "memory")

// ---------------- 256x256 bf16 GEMM, 1 barrier per K-tile -------------------
// 512 threads = 8 waves (2 M-waves x 4 N-waves). BK=64, dbuf LDS 128 KiB.
// LDS per half: 16x32-elem subtiles (1 KiB); quad slot = (col>>3) ^ ((r>>1)&3)
// (0 bank conflicts, verified round 3). Per-wave ds_reads pipelined one phase
// ahead with counted lgkmcnt; cross-wave sync only at the K-tile boundary:
// vmcnt(4) [A(T+1),B(T+1) landed; B(T+2) stays in flight] + s_barrier.
__global__ __launch_bounds__(512, 2)
void gemm_bf16_kernel(const u16* __restrict__ A,   // [Mdim][Kdim] bf16
                      const u16* __restrict__ B,   // [Ndim][Kdim] bf16
                      const float* __restrict__ bias,
                      float* __restrict__ C) {
  __shared__ u16 AsF[32768];   // [buf][half][8192 elems] = 64 KiB
  __shared__ u16 BsF[32768];

  const int t    = threadIdx.x;
  const int lane = t & 63;
  const int w    = t >> 6;      // wave 0..7
  const int wm   = w >> 2;      // 0..1  -> A rows wm*128..+127
  const int wn   = w & 3;       // 0..3  -> B rows wn*64..+63
  const int fr   = lane & 15;
  const int fq   = lane >> 4;
  const int cswz = (fr & 6) << 2;   // ((fr>>1)&3)*8

  // T1: XCD-aware block swizzle (512 blocks, 512%8==0 -> simple form OK)
  const int bid = blockIdx.x;
  const int swz = (bid & 7) * 64 + (bid >> 3);
  const int m0 = (swz >> 4) * 256;   // 32 M-tiles
  const int n0 = (swz & 15) * 256;   // 16 N-tiles

  // staging geometry: chunk c = l*512 + w*64 + lane (16 B each), LDS linear.
  const int c0   = w * 64 + lane;                    // chunk for l=0
  const int r16s = (c0 & 63) >> 2;
  const int srow = ((c0 >> 7) << 4) + r16s;          // 0..63 (l=1 -> +64)
  const int scol = ((c0 >> 6) & 1) * 32 + (((c0 & 3) * 8) ^ ((r16s & 6) << 2));
  const u16* pA = A + (size_t)(m0 + srow) * Kdim + scol;
  const u16* pB = B + (size_t)(n0 + srow) * Kdim + scol;
  const int dsto = c0 * 8;                           // LDS elem offset

  // fragment read offsets (elements): (rt*2+kk)*512 + fr*32 + swizzled col
  const int aoff = wm * 8192 + fr * 32 + ((fq * 8) ^ cswz);
  const int boff = (wn >> 1) * 8192 + (wn & 1) * 4096 + fr * 32 + ((fq * 8) ^ cswz);

  f32x4 acc[8][4] = {};
  short8 bf[2][4];      // [kk][ni], refreshed at tile boundary
  short8 afA[2][2];     // even-q A frags (q0, q2)
  short8 afB[2][2];     // odd-q  A frags (q1, q3)

  auto stageA = [&](int tk, int h) {
    const u16* s = pA + (size_t)h * (128 * Kdim) + tk * 64;
    u16* d = &AsF[((tk & 1) * 2 + h) * 8192 + dsto];
    async16(s, d);
    async16(s + (size_t)(64 * Kdim), d + 4096);
  };
  auto stageB = [&](int tk, int h) {
    const u16* s = pB + (size_t)h * (128 * Kdim) + tk * 64;
    u16* d = &BsF[((tk & 1) * 2 + h) * 8192 + dsto];
    async16(s, d);
    async16(s + (size_t)(64 * Kdim), d + 4096);
  };
  auto rdB_kk = [&](int buf, int kk) {
#pragma unroll
    for (int ni = 0; ni < 4; ++ni)
      bf[kk][ni] = *(const short8*)&BsF[buf * 16384 + boff + (ni * 2 + kk) * 512];
  };
  auto rdA_A = [&](int buf, int q) {
#pragma unroll
    for (int kk = 0; kk < 2; ++kk)
#pragma unroll
      for (int i = 0; i < 2; ++i)
        afA[kk][i] = *(const short8*)&AsF[buf * 16384 + aoff + ((q * 2 + i) * 2 + kk) * 512];
  };
  auto rdA_B = [&](int buf, int q) {
#pragma unroll
    for (int kk = 0; kk < 2; ++kk)
#pragma unroll
      for (int i = 0; i < 2; ++i)
        afB[kk][i] = *(const short8*)&AsF[buf * 16384 + aoff + ((q * 2 + i) * 2 + kk) * 512];
  };
  auto mfmaE = [&](int q) {   // uses afA
    __builtin_amdgcn_s_setprio(1);
#pragma unroll
    for (int kk = 0; kk < 2; ++kk)
#pragma unroll
      for (int i = 0; i < 2; ++i)
#pragma unroll
        for (int ni = 0; ni < 4; ++ni)
          acc[q * 2 + i][ni] = __builtin_amdgcn_mfma_f32_16x16x32_bf16(
              afA[kk][i], bf[kk][ni], acc[q * 2 + i][ni], 0, 0, 0);
    __builtin_amdgcn_s_setprio(0);
  };
  auto mfmaO = [&](int q) {   // uses afB
    __builtin_amdgcn_s_setprio(1);
#pragma unroll
    for (int kk = 0; kk < 2; ++kk)
#pragma unroll
      for (int i = 0; i < 2; ++i)
#pragma unroll
        for (int ni = 0; ni < 4; ++ni)
          acc[q * 2 + i][ni] = __builtin_amdgcn_mfma_f32_16x16x32_bf16(
              afB[kk][i], bf[kk][ni], acc[q * 2 + i][ni], 0, 0, 0);
    __builtin_amdgcn_s_setprio(0);
  };
  auto mfmaO_kk = [&](int q, int kk) {   // one kk-half of an odd q
    __builtin_amdgcn_s_setprio(1);
#pragma unroll
    for (int i = 0; i < 2; ++i)
#pragma unroll
      for (int ni = 0; ni < 4; ++ni)
        acc[q * 2 + i][ni] = __builtin_amdgcn_mfma_f32_16x16x32_bf16(
            afB[kk][i], bf[kk][ni], acc[q * 2 + i][ni], 0, 0, 0);
    __builtin_amdgcn_s_setprio(0);
  };

  // Tile T (BUF=T&1). Entry invariant (per wave): afA=q0 frags, bf=B(T);
  // 12 boundary ds_reads in flight; vmem outstanding = 8 (A(T+1)? no —
  // B(T+1)=4 from T-1; A(T+1)/B(T+2) issued below).
  // MODE: 0 normal (vmcnt(4)); 1 tile 62 (no B stage, vmcnt(0)); 2 last.
#define KT(TK, BUF, DOA, DOB, MODE)                                     \
  {                                                                     \
    /* p0 */                                                            \
    rdA_B((BUF), 1);                                                    \
    if (DOA) stageA((TK) + 1, 0);                                       \
    LGKM4();                 /* boundary 12 done; q1 reads in flight */ \
    mfmaE(0);                                                           \
    /* p1 */                                                            \
    rdA_A((BUF), 2);                                                    \
    if (DOA) stageA((TK) + 1, 1);                                       \
    if (DOB) stageB((TK) + 2, 0);                                       \
    LGKM4();                 /* q1 done */                              \
    mfmaO(1);                                                           \
    /* p2 */                                                            \
    rdA_B((BUF), 3);                                                    \
    if (DOB) stageB((TK) + 2, 1);                                       \
    LGKM4();                 /* q2 done */                              \
    mfmaE(2);                                                           \
    /* p3: the one cross-wave sync point per K-tile */                  \
    if ((MODE) == 0) { VMC4(); } else if ((MODE) == 1) { VMC0(); }      \
    BAR();                   /* all waves: A(T+1)/B(T+1) landed */      \
    LGKM0();                 /* q3 reads done */                        \
    mfmaO_kk(3, 0);                                                     \
    if ((MODE) < 2) rdB_kk((BUF) ^ 1, 0);                               \
    mfmaO_kk(3, 1);                                                     \
    if ((MODE) < 2) { rdB_kk((BUF) ^ 1, 1); rdA_A((BUF) ^ 1, 0); }      \
  }

  // Prologue: stage A(0),B(0),B(1); vmcnt(4) leaves B(1) in flight; barrier;
  // boundary reads for tile 0.
  stageA(0, 0); stageA(0, 1); stageB(0, 0); stageB(0, 1);
  stageB(1, 0); stageB(1, 1);
  VMC4();
  BAR();
  rdB_kk(0, 0); rdB_kk(0, 1); rdA_A(0, 0);

  for (int t2 = 0; t2 < 31; ++t2) {       // K-tiles 0..61
    const int k0 = 2 * t2;
    KT(k0,     0, 1, 1, 0);
    KT(k0 + 1, 1, 1, 1, 0);
  }
  KT(62, 0, 1, 0, 1);                     // stage A(63); drain vmcnt to 0
  KT(63, 1, 0, 0, 2);                     // last: no staging, no boundary

  // Epilogue: C/D map col=lane&15, row=(lane>>4)*4+j  [m89]
  float bv[4];
#pragma unroll
  for (int ni = 0; ni < 4; ++ni)
    bv[ni] = bias[n0 + wn * 64 + ni * 16 + fr];

#pragma unroll
  for (int mi = 0; mi < 8; ++mi) {
#pragma unroll
    for (int j = 0; j < 4; ++j) {
      const int row = m0 + wm * 128 + mi * 16 + fq * 4 + j;
      float* cp = C + (size_t)row * Ndim + n0 + wn * 64 + fr;
#pragma unroll
      for (int ni = 0; ni < 4; ++ni)
        cp[ni * 16] = acc[mi][ni][j] + bv[ni];
    }
  }
#undef KT
}

extern "C" void kernel_launch(void* const* d_in, const int* in_sizes, int n_in,
                              void* d_out, int out_size, void* d_ws, size_t ws_size,
                              hipStream_t stream) {
  const float* x    = (const float*)d_in[0];   // [8192][4096] fp32
  const float* cent = (const float*)d_in[1];   // [256] fp32
  const float* bias = (const float*)d_in[2];   // [4096] fp32
  const int*   idx  = (const int*)d_in[3];     // [4096][4096] int
  float* out = (float*)d_out;                  // [8192][4096] fp32

  u16* wb = (u16*)d_ws;
  u16* xb = (u16*)((char*)d_ws + (size_t)Ndim * Kdim * sizeof(u16));

  decode_weight_kernel<<<(Ndim * Kdim) / (256 * 8), 256, 0, stream>>>(idx, cent, wb);
  cvt_x_kernel<<<((size_t)Mdim * Kdim) / (256 * 8), 256, 0, stream>>>(x, xb);

  gemm_bf16_kernel<<<dim3(512), 512, 0, stream>>>(xb, wb, bias, out);
}